// Round 5
// baseline (463.447 us; speedup 1.0000x reference)
//
#include <hip/hip_runtime.h>
#include <stdint.h>
#include <math.h>

#define SS 8
#define NBLK 8192
#define DIN 512
#define DOUT 256
#define GB 8              // graph blocks per WG
#define MT 64             // rows per WG
#define BK 32             // K chunk
#define KSTEPS 16         // DIN/BK
#define VSTR 264          // anchor bf16 LDS stride
#define EPSN 1e-12f

typedef __bf16 bf16;
typedef __bf16 bf16x8 __attribute__((ext_vector_type(8)));
typedef float  f32x4  __attribute__((ext_vector_type(4)));

__device__ __forceinline__ bf16x8 cvt8(f32x4 lo, f32x4 hi) {
    bf16x8 r;
    r[0] = (bf16)lo[0]; r[1] = (bf16)lo[1]; r[2] = (bf16)lo[2]; r[3] = (bf16)lo[3];
    r[4] = (bf16)hi[0]; r[5] = (bf16)hi[1]; r[6] = (bf16)hi[2]; r[7] = (bf16)hi[3];
    return r;
}

// ---- prep: Wt = W_gcn^T in bf16 [n][k]; W_bil split into bf16 hi+lo ----
__global__ void prep_kernel(const float* __restrict__ W_gcn,
                            const float* __restrict__ W_bil,
                            bf16* __restrict__ Wt,
                            bf16* __restrict__ Wh,
                            bf16* __restrict__ Wl) {
    int idx = blockIdx.x * 256 + threadIdx.x;   // 196608 total
    if (idx < DIN * DOUT) {
        int k = idx >> 8, n = idx & 255;
        Wt[n * DIN + k] = (bf16)W_gcn[idx];
    } else {
        int j = idx - DIN * DOUT;               // < 65536
        float wv = W_bil[j];
        bf16 h = (bf16)wv;
        Wh[j] = h;
        Wl[j] = (bf16)(wv - (float)h);
    }
}

// ---- barrier-free K-pass: acc += X[row0:row0+64] @ Wt^T, frags direct from global ----
__device__ __forceinline__ void kpass(const float* __restrict__ xb,
                                      const bf16* __restrict__ Wt,
                                      int row0, int w, int q, int r15,
                                      f32x4 acc[4][4])
{
#pragma unroll
    for (int mi = 0; mi < 4; ++mi)
#pragma unroll
        for (int ni = 0; ni < 4; ++ni) acc[mi][ni] = (f32x4){0.f, 0.f, 0.f, 0.f};

    // A: lane (q,r15) needs x[row0 + mi*16 + r15][s*32 + q*8 .. +8)   (32 B)
    // B: lane (q,r15) needs Wt[w*64 + ni*16 + r15][s*32 + q*8 .. +8)  (16 B bf16)
    const float* ax = xb + (size_t)(row0 + r15) * DIN + q * 8;
    const bf16*  bx = Wt + (size_t)(w * 64 + r15) * DIN + q * 8;

    f32x4  pl[4], ph[4];
    bf16x8 pb[4];
#pragma unroll
    for (int mi = 0; mi < 4; ++mi) {
        pl[mi] = *(const f32x4*)(ax + mi * 16 * DIN);
        ph[mi] = *(const f32x4*)(ax + mi * 16 * DIN + 4);
    }
#pragma unroll
    for (int ni = 0; ni < 4; ++ni)
        pb[ni] = *(const bf16x8*)(bx + ni * 16 * DIN);

#pragma unroll 2
    for (int s = 0; s < KSTEPS; ++s) {
        bf16x8 af[4], bfr[4];
#pragma unroll
        for (int mi = 0; mi < 4; ++mi) af[mi] = cvt8(pl[mi], ph[mi]);
#pragma unroll
        for (int ni = 0; ni < 4; ++ni) bfr[ni] = pb[ni];

        if (s + 1 < KSTEPS) {                   // prefetch next step
            const int o = (s + 1) * BK;
#pragma unroll
            for (int mi = 0; mi < 4; ++mi) {
                pl[mi] = *(const f32x4*)(ax + mi * 16 * DIN + o);
                ph[mi] = *(const f32x4*)(ax + mi * 16 * DIN + o + 4);
            }
#pragma unroll
            for (int ni = 0; ni < 4; ++ni)
                pb[ni] = *(const bf16x8*)(bx + ni * 16 * DIN + o);
        }
#pragma unroll
        for (int mi = 0; mi < 4; ++mi)
#pragma unroll
            for (int ni = 0; ni < 4; ++ni)
                acc[mi][ni] = __builtin_amdgcn_mfma_f32_16x16x32_bf16(
                    af[mi], bfr[ni], acc[mi][ni], 0, 0, 0);
    }
}

__global__ __launch_bounds__(256, 3) void cola_fused5(
    const float* __restrict__ pos_x, const float* __restrict__ neg_x,
    const int* __restrict__ pos_src, const int* __restrict__ pos_dst,
    const float* __restrict__ pos_w,
    const int* __restrict__ neg_src, const int* __restrict__ neg_dst,
    const float* __restrict__ neg_w,
    const bf16* __restrict__ Wt, const bf16* __restrict__ Wh,
    const bf16* __restrict__ Wl,
    const float* __restrict__ b_gcn, const float* __restrict__ prelu_a,
    const float* __restrict__ b_bil, float* __restrict__ out)
{
    __shared__ float pool_pos[GB * DOUT];    // 8 KB
    __shared__ float v_lds[GB * DOUT];       // 8 KB
    __shared__ bf16  ahs[GB * VSTR];         // 4.125 KB
    __shared__ bf16  als[GB * VSTR];         // 4.125 KB
    __shared__ float adjP[GB][SS][SS];       // 2 KB
    __shared__ float adjN[GB][SS][SS];       // 2 KB
    __shared__ float red[5 * GB];            // ssqP|ssqA|ssqN|scoreP|scoreN

    const int t    = threadIdx.x;
    const int wg   = blockIdx.x;
    const int w    = t >> 6;
    const int lane = t & 63;
    const int q    = lane >> 4;
    const int r15  = lane & 15;
    const int row0 = wg * MT;

    // ---- zero adjacency + reductions ----
    for (int i = t; i < GB * 64; i += 256) { ((float*)adjP)[i] = 0.f; ((float*)adjN)[i] = 0.f; }
    if (t < 5 * GB) red[t] = 0.f;
    __syncthreads();

    // ---- build weighted adjacency (edges block-contiguous, 64/block) ----
    {
        int2   sp2 = ((const int2*)pos_src)[wg * 256 + t];
        int2   dp2 = ((const int2*)pos_dst)[wg * 256 + t];
        float2 wp2 = ((const float2*)pos_w)[wg * 256 + t];
        int2   sn2 = ((const int2*)neg_src)[wg * 256 + t];
        int2   dn2 = ((const int2*)neg_dst)[wg * 256 + t];
        float2 wn2 = ((const float2*)neg_w)[wg * 256 + t];
        int gl = t >> 5;
        int base = (wg * GB + gl) * SS;
        atomicAdd(&adjP[gl][dp2.x - base][sp2.x - base], wp2.x);
        atomicAdd(&adjP[gl][dp2.y - base][sp2.y - base], wp2.y);
        atomicAdd(&adjN[gl][dn2.x - base][sn2.x - base], wn2.x);
        atomicAdd(&adjN[gl][dn2.y - base][sn2.y - base], wn2.y);
    }
    __syncthreads();    // adj + red visible to all waves

    const float pa = *prelu_a;
    f32x4 acc[4][4];

    // ================= POS: K-pass (barrier-free) + epilogue ==================
    kpass(pos_x, Wt, row0, w, q, r15, acc);

#pragma unroll
    for (int mi = 0; mi < 4; ++mi) {
        const int gl = mi * 2 + (q >> 1);
        float part = 0.f;
#pragma unroll
        for (int ni = 0; ni < 4; ++ni) {
            float r0, r1, r2, r3, r4, r5, r6, r7;
#pragma unroll
            for (int r = 0; r < 4; ++r) {
                float own = acc[mi][ni][r];
                float oth = __shfl_xor(own, 16);
                float lo = ((q & 1) == 0) ? own : oth;
                float hi = ((q & 1) == 0) ? oth : own;
                if (r == 0) { r0 = lo; r4 = hi; }
                else if (r == 1) { r1 = lo; r5 = hi; }
                else if (r == 2) { r2 = lo; r6 = hi; }
                else            { r3 = lo; r7 = hi; }
            }
            int c = w * 64 + ni * 16 + r15;
            float bg = b_gcn[c];
            float pool = 0.f, anch = 0.f;
#pragma unroll
            for (int d = 0; d < 8; ++d) {
                const float* ar = &adjP[gl][d][0];
                float a = bg + ar[0]*r0 + ar[1]*r1 + ar[2]*r2 + ar[3]*r3
                             + ar[4]*r4 + ar[5]*r5 + ar[6]*r6 + ar[7]*r7;
                float h = (a >= 0.f) ? a : pa * a;
                if (d < 7) pool += h; else anch = h;
            }
            float pl = pool * (1.f / 7.f);
            if ((q & 1) == 0) {
                pool_pos[gl * DOUT + c] = pl;
                part += pl * pl;
            } else {
                bf16 hh = (bf16)anch;
                ahs[gl * VSTR + c] = hh;
                als[gl * VSTR + c] = (bf16)(anch - (float)hh);
                part += anch * anch;
            }
        }
        part += __shfl_xor(part, 8);
        part += __shfl_xor(part, 4);
        part += __shfl_xor(part, 2);
        part += __shfl_xor(part, 1);
        if (r15 == 0) atomicAdd((q & 1) ? &red[GB + gl] : &red[gl], part);
    }
    __syncthreads();

    // ================= v = W_bil . anchor  (3-term bf16 split MFMA) ===========
    {
        f32x4 accv[4];
#pragma unroll
        for (int ni = 0; ni < 4; ++ni) accv[ni] = (f32x4){0.f, 0.f, 0.f, 0.f};
        const int ga = (r15 & 7) * VSTR;        // rows 8..15 duplicate 0..7
#pragma unroll
        for (int ks = 0; ks < 8; ++ks) {
            bf16x8 ah_f = *(const bf16x8*)(ahs + ga + ks * 32 + q * 8);
            bf16x8 al_f = *(const bf16x8*)(als + ga + ks * 32 + q * 8);
#pragma unroll
            for (int ni = 0; ni < 4; ++ni) {
                int d = w * 64 + ni * 16 + r15;
                bf16x8 bh = *(const bf16x8*)(Wh + (size_t)d * DOUT + ks * 32 + q * 8);
                bf16x8 bl = *(const bf16x8*)(Wl + (size_t)d * DOUT + ks * 32 + q * 8);
                accv[ni] = __builtin_amdgcn_mfma_f32_16x16x32_bf16(ah_f, bh, accv[ni], 0, 0, 0);
                accv[ni] = __builtin_amdgcn_mfma_f32_16x16x32_bf16(al_f, bh, accv[ni], 0, 0, 0);
                accv[ni] = __builtin_amdgcn_mfma_f32_16x16x32_bf16(ah_f, bl, accv[ni], 0, 0, 0);
            }
        }
        float sp[4] = {0.f, 0.f, 0.f, 0.f};
        if (q < 2) {
#pragma unroll
            for (int ni = 0; ni < 4; ++ni) {
                int c = w * 64 + ni * 16 + r15;
#pragma unroll
                for (int r = 0; r < 4; ++r) {
                    int g = q * 4 + r;
                    v_lds[g * DOUT + c] = accv[ni][r];
                    sp[r] += accv[ni][r] * pool_pos[g * DOUT + c];
                }
            }
        }
#pragma unroll
        for (int r = 0; r < 4; ++r) {
            sp[r] += __shfl_xor(sp[r], 8);
            sp[r] += __shfl_xor(sp[r], 4);
            sp[r] += __shfl_xor(sp[r], 2);
            sp[r] += __shfl_xor(sp[r], 1);
        }
        if (q < 2 && r15 == 0) {
#pragma unroll
            for (int r = 0; r < 4; ++r) atomicAdd(&red[3 * GB + q * 4 + r], sp[r]);
        }
    }
    __syncthreads();    // v_lds visible before neg epilogue

    // ================= NEG: K-pass (barrier-free, acc reused) + epilogue ======
    kpass(neg_x, Wt, row0, w, q, r15, acc);

#pragma unroll
    for (int mi = 0; mi < 4; ++mi) {
        const int gl = mi * 2 + (q >> 1);
        float part = 0.f;
#pragma unroll
        for (int ni = 0; ni < 4; ++ni) {
            float r0, r1, r2, r3, r4, r5, r6, r7;
#pragma unroll
            for (int r = 0; r < 4; ++r) {
                float own = acc[mi][ni][r];
                float oth = __shfl_xor(own, 16);
                float lo = ((q & 1) == 0) ? own : oth;
                float hi = ((q & 1) == 0) ? oth : own;
                if (r == 0) { r0 = lo; r4 = hi; }
                else if (r == 1) { r1 = lo; r5 = hi; }
                else if (r == 2) { r2 = lo; r6 = hi; }
                else            { r3 = lo; r7 = hi; }
            }
            int c = w * 64 + ni * 16 + r15;
            float bg = b_gcn[c];
            float pool = 0.f;
#pragma unroll
            for (int d = 0; d < 7; ++d) {
                const float* ar = &adjN[gl][d][0];
                float a = bg + ar[0]*r0 + ar[1]*r1 + ar[2]*r2 + ar[3]*r3
                             + ar[4]*r4 + ar[5]*r5 + ar[6]*r6 + ar[7]*r7;
                float h = (a >= 0.f) ? a : pa * a;
                pool += h;
            }
            float pl = pool * (1.f / 7.f);
            part += ((q & 1) == 0) ? pl * v_lds[gl * DOUT + c] : pl * pl;
        }
        part += __shfl_xor(part, 8);
        part += __shfl_xor(part, 4);
        part += __shfl_xor(part, 2);
        part += __shfl_xor(part, 1);
        if (r15 == 0) atomicAdd((q & 1) ? &red[2 * GB + gl] : &red[4 * GB + gl], part);
    }
    __syncthreads();

    // ================= finalize ===============================================
    if (t < GB) {
        float np = fmaxf(sqrtf(red[t]), EPSN);
        float na = fmaxf(sqrtf(red[GB + t]), EPSN);
        float nn = fmaxf(sqrtf(red[2 * GB + t]), EPSN);
        float bb = b_bil[0];
        out[wg * GB + t]        = red[3 * GB + t] / (np * na) + bb;
        out[NBLK + wg * GB + t] = red[4 * GB + t] / (nn * na) + bb;
    }
}

extern "C" void kernel_launch(void* const* d_in, const int* in_sizes, int n_in,
                              void* d_out, int out_size, void* d_ws, size_t ws_size,
                              hipStream_t stream) {
    const float* pos_x   = (const float*)d_in[0];
    const float* neg_x   = (const float*)d_in[1];
    const int*   pos_src = (const int*)d_in[2];
    const int*   pos_dst = (const int*)d_in[3];
    const float* pos_w   = (const float*)d_in[4];
    const int*   neg_src = (const int*)d_in[5];
    const int*   neg_dst = (const int*)d_in[6];
    const float* neg_w   = (const float*)d_in[7];
    const float* W_gcn   = (const float*)d_in[8];
    const float* b_gcn   = (const float*)d_in[9];
    const float* prelu_a = (const float*)d_in[10];
    const float* W_bil   = (const float*)d_in[11];
    const float* b_bil   = (const float*)d_in[12];
    float* outp = (float*)d_out;

    bf16* Wt = (bf16*)d_ws;                 // 256 KB
    bf16* Wh = Wt + DIN * DOUT;             // 128 KB
    bf16* Wl = Wh + DOUT * DOUT;            // 128 KB

    prep_kernel<<<(DIN * DOUT + DOUT * DOUT) / 256, 256, 0, stream>>>(W_gcn, W_bil, Wt, Wh, Wl);
    cola_fused5<<<NBLK / GB, 256, 0, stream>>>(
        pos_x, neg_x, pos_src, pos_dst, pos_w, neg_src, neg_dst, neg_w,
        Wt, Wh, Wl, b_gcn, prelu_a, b_bil, outp);
}